// Round 14
// baseline (186.159 us; speedup 1.0000x reference)
//
#include <hip/hip_runtime.h>
#include <hip/hip_bf16.h>

typedef unsigned short u16;
typedef __bf16 bf16x8 __attribute__((ext_vector_type(8)));
typedef float f32x4 __attribute__((ext_vector_type(4)));

__device__ __forceinline__ u16 f2bf(float f) {
    unsigned int u = __builtin_bit_cast(unsigned int, f);
    unsigned int r = u + 0x7FFFu + ((u >> 16) & 1u);
    return (u16)(r >> 16);
}

__device__ __forceinline__ void gload_lds16(const u16* g, u16* l) {
    __builtin_amdgcn_global_load_lds(
        (const __attribute__((address_space(1))) void*)(g),
        (__attribute__((address_space(3))) void*)(l), 16, 0, 0);
}

// ---- all fp32->bf16 converts in ONE launch ----
__global__ __launch_bounds__(256) void cvt_all(
    const float* __restrict__ x, const float* __restrict__ Wq,
    const float* __restrict__ Wk, const float* __restrict__ Wv,
    u16* __restrict__ xb, u16* __restrict__ wqkv)
{
    long long b = blockIdx.x;
    const float* src;
    u16* dst;
    long long i8;
    if (b < 4096) {
        src = x; dst = xb; i8 = b * 256 + threadIdx.x;
    } else {
        int wsel = (int)((b - 4096) >> 9);              // 0,1,2
        src = (wsel == 0) ? Wq : ((wsel == 1) ? Wk : Wv);
        dst = wqkv + (long long)wsel * 1024 * 1024;
        i8 = ((b - 4096) & 511) * 256 + threadIdx.x;
    }
    const float4* p = (const float4*)src + 2 * i8;
    float4 a = p[0], c = p[1];
    uint4 o;
    o.x = (unsigned)f2bf(a.x) | ((unsigned)f2bf(a.y) << 16);
    o.y = (unsigned)f2bf(a.z) | ((unsigned)f2bf(a.w) << 16);
    o.z = (unsigned)f2bf(c.x) | ((unsigned)f2bf(c.y) << 16);
    o.w = (unsigned)f2bf(c.z) | ((unsigned)f2bf(c.w) << 16);
    ((uint4*)dst)[i8] = o;
}

// ------- 4-phase bf16 GEMM body (r7/r11/r13 proven), C = A[M,K]*B[N,K]^T -------
// BM=256, BK=64, 512 thr = 8 waves. BN=256: 2x4 waves; BN=128: 4x2 waves.
// Subtiled LDS (conflict-free ds_read_b128, linear gload_lds); region-staggered
// staging; counted vmcnt once/tile; XCD-bijective chunk swizzle from flat id.
// EPI: 0 plain bf16; 1 exp2(acc*k) bf16 + row partials aux[row*8+bx];
//      2 f32 scaled by 1/sum(aux[row*8+0..7]) (inv hoisted BEFORE K-loop).
template <int BN, bool OUT_F32, int EPI>
__device__ __forceinline__ void gemm_body(
    u16* lds,
    const u16* __restrict__ A, const u16* __restrict__ B, void* __restrict__ Cv,
    int lda, int ldb, int ldc, int K,
    long long sAz, long long sBz, long long sCz,
    int z, int flat, int gx, int cw, int ch,
    float* __restrict__ aux)
{
    constexpr int WC = (BN == 256) ? 4 : 2;
    constexpr int ROWS = (BN == 256) ? 128 : 64;
    constexpr int MI = ROWS / 16;
    constexpr int MIh = MI / 2;
    constexpr int BLOADS = BN / 64;
    constexpr int BNK = BN * 64;

    u16* ldsB = lds + 32768;

    const int xcd = flat & 7, jj = flat >> 3;
    const int nCx = gx / cw;
    const int bx = (xcd % nCx) * cw + jj % cw;
    const int by = (xcd / nCx) * ch + jj / cw;

    A += (long long)z * sAz;
    B += (long long)z * sBz;

    const int tid  = threadIdx.x;
    const int lane = tid & 63;
    const int wave = tid >> 6;
    const int wr = wave / WC, wc = wave % WC;
    const int m0 = by << 8, n0 = bx * BN;
    const int NT = K >> 6;

    // epilogue coordinates (needed early for EPI==2 hoist)
    const int fl = lane & 15, fg = lane >> 4;
    const int er0 = m0 + wr * ROWS + fg * 4;
    const int ec0 = n0 + wc * 64 + fl;

    // EPI==2: hoist inverse row-sums before the K-loop (loads overlap GEMM;
    // they are oldest vmem ops so in-loop counted vmcnt waits stay conservative)
    float iv[MI][4];
    if constexpr (EPI == 2) {
#pragma unroll
        for (int mi = 0; mi < MI; ++mi)
#pragma unroll
            for (int j = 0; j < 4; ++j) {
                const float* pr = aux + ((long long)z * 2048 + er0 + mi * 16 + j) * 8;
                float s = 0.f;
#pragma unroll
                for (int k = 0; k < 8; ++k) s += pr[k];
                iv[mi][j] = 1.0f / s;
            }
    }

    const u16* gAp[4];
    const u16* gBp[BLOADS];
#pragma unroll
    for (int i = 0; i < 4; ++i) {
        int s = tid + i * 512, row = ((s >> 7) << 4) | (s & 15), g = (s >> 4) & 7;
        gAp[i] = A + (long long)(m0 + row) * lda + g * 8;
    }
#pragma unroll
    for (int i = 0; i < BLOADS; ++i) {
        int s = tid + i * 512, row = ((s >> 7) << 4) | (s & 15), g = (s >> 4) & 7;
        gBp[i] = B + (long long)(n0 + row) * ldb + g * 8;
    }
    auto stA = [&](int kt, int buf, int i) {
        gload_lds16(gAp[i] + (long long)kt * 64, lds + buf * 16384 + (tid + i * 512) * 8);
    };
    auto stB = [&](int kt, int buf, int i) {
        gload_lds16(gBp[i] + (long long)kt * 64, ldsB + buf * BNK + (tid + i * 512) * 8);
    };

    f32x4 acc[MI][4] = {};

#pragma unroll
    for (int i = 0; i < 4; ++i) stA(0, 0, i);
#pragma unroll
    for (int i = 0; i < BLOADS; ++i) stB(0, 0, i);
#pragma unroll
    for (int i = 0; i < 4; ++i) stA(1, 1, i);
#pragma unroll
    for (int i = 0; i < BLOADS; ++i) stB(1, 1, i);
    if constexpr (BN == 256) asm volatile("s_waitcnt vmcnt(8)" ::: "memory");
    else                     asm volatile("s_waitcnt vmcnt(6)" ::: "memory");
    __builtin_amdgcn_s_barrier();

#pragma unroll 2
    for (int kt = 0; kt < NT; ++kt) {
        const int cur = kt & 1;
        const u16* sAc = lds  + cur * 16384 + lane * 8;
        const u16* sBc = ldsB + cur * BNK   + lane * 8;
        const bool st = (kt + 2 < NT);

        bf16x8 a[MIh][2], b0[2][2], b1[2][2];

        // ===== p0: read A-lo + B-lo; MFMA Q00 =====
#pragma unroll
        for (int mi = 0; mi < MIh; ++mi)
#pragma unroll
            for (int kk = 0; kk < 2; ++kk)
                a[mi][kk] = *(const bf16x8*)(sAc + ((wr * MI + mi) * 8 + kk * 4) * 128);
#pragma unroll
        for (int ni = 0; ni < 2; ++ni)
#pragma unroll
            for (int kk = 0; kk < 2; ++kk)
                b0[ni][kk] = *(const bf16x8*)(sBc + ((wc * 4 + ni) * 8 + kk * 4) * 128);
        __builtin_amdgcn_s_barrier();
        asm volatile("s_waitcnt lgkmcnt(0)" ::: "memory");
        __builtin_amdgcn_s_setprio(1);
#pragma unroll
        for (int kk = 0; kk < 2; ++kk)
#pragma unroll
            for (int mi = 0; mi < MIh; ++mi)
#pragma unroll
                for (int ni = 0; ni < 2; ++ni)
                    acc[mi][ni] = __builtin_amdgcn_mfma_f32_16x16x32_bf16(
                        a[mi][kk], b0[ni][kk], acc[mi][ni], 0, 0, 0);
        __builtin_amdgcn_s_setprio(0);
        __builtin_amdgcn_s_barrier();

        // ===== p1: stage A-lo regions; read B-hi; MFMA Q01 =====
        if constexpr (BN == 256) {
            if (st) { stA(kt + 2, cur, 0); stA(kt + 2, cur, 2); }
        }
#pragma unroll
        for (int ni = 0; ni < 2; ++ni)
#pragma unroll
            for (int kk = 0; kk < 2; ++kk)
                b1[ni][kk] = *(const bf16x8*)(sBc + ((wc * 4 + 2 + ni) * 8 + kk * 4) * 128);
        __builtin_amdgcn_s_barrier();
        asm volatile("s_waitcnt lgkmcnt(0)" ::: "memory");
        __builtin_amdgcn_s_setprio(1);
#pragma unroll
        for (int kk = 0; kk < 2; ++kk)
#pragma unroll
            for (int mi = 0; mi < MIh; ++mi)
#pragma unroll
                for (int ni = 0; ni < 2; ++ni)
                    acc[mi][2 + ni] = __builtin_amdgcn_mfma_f32_16x16x32_bf16(
                        a[mi][kk], b1[ni][kk], acc[mi][2 + ni], 0, 0, 0);
        __builtin_amdgcn_s_setprio(0);
        __builtin_amdgcn_s_barrier();

        // ===== p2: stage B-lo; read A-hi; MFMA Q10 =====
        if (st) {
            if constexpr (BN == 256) { stB(kt + 2, cur, 0); stB(kt + 2, cur, 1); }
            else                     { stB(kt + 2, cur, 0); }
        }
#pragma unroll
        for (int mi = 0; mi < MIh; ++mi)
#pragma unroll
            for (int kk = 0; kk < 2; ++kk)
                a[mi][kk] = *(const bf16x8*)(sAc + ((wr * MI + MIh + mi) * 8 + kk * 4) * 128);
        __builtin_amdgcn_s_barrier();
        asm volatile("s_waitcnt lgkmcnt(0)" ::: "memory");
        __builtin_amdgcn_s_setprio(1);
#pragma unroll
        for (int kk = 0; kk < 2; ++kk)
#pragma unroll
            for (int mi = 0; mi < MIh; ++mi)
#pragma unroll
                for (int ni = 0; ni < 2; ++ni)
                    acc[MIh + mi][ni] = __builtin_amdgcn_mfma_f32_16x16x32_bf16(
                        a[mi][kk], b0[ni][kk], acc[MIh + mi][ni], 0, 0, 0);
        __builtin_amdgcn_s_setprio(0);
        __builtin_amdgcn_s_barrier();

        // ===== p3: stage A-hi + B-hi; MFMA Q11; counted vmcnt =====
        if (st) {
            if constexpr (BN == 256) {
                stA(kt + 2, cur, 1); stA(kt + 2, cur, 3);
                stB(kt + 2, cur, 2); stB(kt + 2, cur, 3);
            } else {
                stA(kt + 2, cur, 0); stA(kt + 2, cur, 1);
                stA(kt + 2, cur, 2); stA(kt + 2, cur, 3);
                stB(kt + 2, cur, 1);
            }
        }
        __builtin_amdgcn_s_barrier();
        __builtin_amdgcn_s_setprio(1);
#pragma unroll
        for (int kk = 0; kk < 2; ++kk)
#pragma unroll
            for (int mi = 0; mi < MIh; ++mi)
#pragma unroll
                for (int ni = 0; ni < 2; ++ni)
                    acc[MIh + mi][2 + ni] = __builtin_amdgcn_mfma_f32_16x16x32_bf16(
                        a[mi][kk], b1[ni][kk], acc[MIh + mi][2 + ni], 0, 0, 0);
        __builtin_amdgcn_s_setprio(0);
        if (st) {
            if constexpr (BN == 256) asm volatile("s_waitcnt vmcnt(8)" ::: "memory");
            else                     asm volatile("s_waitcnt vmcnt(6)" ::: "memory");
        } else if (kt + 1 < NT) {
            asm volatile("s_waitcnt vmcnt(0)" ::: "memory");
        }
        __builtin_amdgcn_s_barrier();
    }

    // ---- epilogue: C/D layout col = lane&15, row = (lane>>4)*4+j ----
    if constexpr (EPI == 1) {
        // P~ = 2^(acc * log2e/32) -> bf16 C; row partials -> aux[(z*2048+row)*8+bx]
        u16* C = (u16*)Cv + (long long)z * sCz;
        float lsum[MI][4];
#pragma unroll
        for (int mi = 0; mi < MI; ++mi)
#pragma unroll
            for (int j = 0; j < 4; ++j) {
                float s = 0.f;
#pragma unroll
                for (int ni = 0; ni < 4; ++ni) {
                    float e = __builtin_amdgcn_exp2f(acc[mi][ni][j] * 0.04508422f);
                    C[(long long)(er0 + mi * 16 + j) * ldc + ec0 + ni * 16] = f2bf(e);
                    s += e;
                }
                lsum[mi][j] = s;
            }
#pragma unroll
        for (int mi = 0; mi < MI; ++mi)
#pragma unroll
            for (int j = 0; j < 4; ++j)
#pragma unroll
                for (int off = 1; off < 16; off <<= 1)
                    lsum[mi][j] += __shfl_xor(lsum[mi][j], off, 64);
        float (*rsbuf)[4] = reinterpret_cast<float(*)[4]>(lds);
        if (fl == 0) {
#pragma unroll
            for (int mi = 0; mi < MI; ++mi)
#pragma unroll
                for (int j = 0; j < 4; ++j)
                    rsbuf[wr * ROWS + mi * 16 + fg * 4 + j][wc] = lsum[mi][j];
        }
        __syncthreads();
        if (tid < 256) {
            float s = rsbuf[tid][0] + rsbuf[tid][1] + rsbuf[tid][2] + rsbuf[tid][3];
            aux[((long long)z * 2048 + m0 + tid) * 8 + bx] = s;
        }
    } else if constexpr (EPI == 2) {
        float* C = (float*)Cv + (long long)z * sCz;
#pragma unroll
        for (int mi = 0; mi < MI; ++mi)
#pragma unroll
            for (int ni = 0; ni < 4; ++ni)
#pragma unroll
                for (int j = 0; j < 4; ++j)
                    C[(long long)(er0 + mi * 16 + j) * ldc + ec0 + ni * 16] =
                        acc[mi][ni][j] * iv[mi][j];
    } else if constexpr (OUT_F32) {
        float* C = (float*)Cv + (long long)z * sCz;
#pragma unroll
        for (int mi = 0; mi < MI; ++mi)
#pragma unroll
            for (int ni = 0; ni < 4; ++ni)
#pragma unroll
                for (int j = 0; j < 4; ++j)
                    C[(long long)(er0 + mi * 16 + j) * ldc + ec0 + ni * 16] = acc[mi][ni][j];
    } else {
        u16* C = (u16*)Cv + (long long)z * sCz;
#pragma unroll
        for (int mi = 0; mi < MI; ++mi)
#pragma unroll
            for (int ni = 0; ni < 4; ++ni)
#pragma unroll
                for (int j = 0; j < 4; ++j)
                    C[(long long)(er0 + mi * 16 + j) * ldc + ec0 + ni * 16] = f2bf(acc[mi][ni][j]);
    }
}

// ---- fused QKV + vT: blocks 0-255 do qk = x*[Wq;Wk]^T (BN=256),
// blocks 256-383 do vT = Wv*x^T (BN=256, grid 32x4, chunk 8x2).
__global__ __launch_bounds__(512, 2) void gemm_fused_qkv_vt(
    const u16* __restrict__ xb, const u16* __restrict__ wqk,
    const u16* __restrict__ wvb, u16* __restrict__ qk, u16* __restrict__ vT,
    int D, int MS)
{
    extern __shared__ u16 lds[];
    const int bid = blockIdx.x;
    if (bid < 256) {
        // qk[8192][2048] = xb * wqk^T : gx=8, gy=32, chunk 8x4
        gemm_body<256, false, 0>(lds, xb, wqk, qk, D, D, 2 * D, D,
                                 0, 0, 0, 0, bid, 8, 8, 4, nullptr);
    } else {
        // vT[1024][8192] = wvb * xb^T : gx=32, gy=4, chunk 8x2
        gemm_body<256, false, 0>(lds, wvb, xb, vT, D, D, MS, D,
                                 0, 0, 0, 0, bid - 256, 32, 8, 2, nullptr);
    }
}

// ---- standalone wrappers for scores / PV (batched via blockIdx.z) ----
template <int BN, bool OUT_F32, int EPI>
__global__ __launch_bounds__(512, 2) void gemm4p(
    const u16* __restrict__ A, const u16* __restrict__ B, void* __restrict__ Cv,
    int lda, int ldb, int ldc, int K,
    long long sAz, long long sBz, long long sCz, int cw, int ch,
    float* __restrict__ aux)
{
    extern __shared__ u16 lds[];
    const int flat = blockIdx.x + gridDim.x * blockIdx.y;
    gemm_body<BN, OUT_F32, EPI>(lds, A, B, Cv, lda, ldb, ldc, K,
                                sAz, sBz, sCz, blockIdx.z, flat,
                                gridDim.x, cw, ch, aux);
}

extern "C" void kernel_launch(void* const* d_in, const int* in_sizes, int n_in,
                              void* d_out, int out_size, void* d_ws, size_t ws_size,
                              hipStream_t stream) {
    const float* x  = (const float*)d_in[0];   // [4,2048,1024]
    const float* Wq = (const float*)d_in[1];   // [1024,1024]
    const float* Wk = (const float*)d_in[2];
    const float* Wv = (const float*)d_in[3];
    float* out = (float*)d_out;                // [4,2048,1024] fp32

    const int B = 4, S = 2048, D = 1024;
    const long long MS = (long long)B * S;     // 8192

    u16* Sc  = (u16*)d_ws;                     // 4*2048*2048
    u16* xb  = Sc;                             // 8192*1024 (overlays Sc; dead after fused GEMM)
    u16* wqk = Sc  + (long long)B * S * S;     // Wq,Wk then Wv (contiguous)
    u16* wvb = wqk + 2 * D * D;
    u16* qk  = wvb + D * D;                    // 8192*2048
    u16* vT  = qk  + MS * 2 * D;               // 1024*8192
    float* partial = (float*)(vT + MS * D);    // 8192*8 f32
    size_t need = (size_t)2 * ((long long)B * S * S + 3 * D * D + MS * 2 * D + MS * D)
                + (size_t)4 * (MS * 8);
    if (ws_size < need) return;

    (void)hipFuncSetAttribute(reinterpret_cast<const void*>(&gemm_fused_qkv_vt),
                        hipFuncAttributeMaxDynamicSharedMemorySize, 131072);
    (void)hipFuncSetAttribute(reinterpret_cast<const void*>(&gemm4p<256, false, 1>),
                        hipFuncAttributeMaxDynamicSharedMemorySize, 131072);
    (void)hipFuncSetAttribute(reinterpret_cast<const void*>(&gemm4p<128, true, 2>),
                        hipFuncAttributeMaxDynamicSharedMemorySize, 98304);

    // 1) all converts in one launch
    cvt_all<<<4096 + 3 * 512, 256, 0, stream>>>(x, Wq, Wk, Wv, xb, wqk);

    // 2) fused: qk = xb*[Wq;Wk]^T (blocks 0-255) + vT = Wv*xb^T (blocks 256-383)
    gemm_fused_qkv_vt<<<384, 512, 131072, stream>>>(
        xb, wqk, wvb, qk, vT, D, (int)MS);

    // 3) P~ = exp(q k^T / 32) bf16 + row partials   grid (8,8,4); chunk 2x4
    gemm4p<256, false, 1><<<dim3(S / 256, S / 256, B), 512, 131072, stream>>>(
        qk, qk + D, Sc, 2 * D, 2 * D, S, D,
        (long long)S * 2 * D, (long long)S * 2 * D, (long long)S * S, 2, 4, partial);

    // 4) out = (P~ * vT^T) * (1/rowsum)   grid (8,8,4); chunk 4x2; fp32 out
    gemm4p<128, true, 2><<<dim3(D / 128, S / 256, B), 512, 98304, stream>>>(
        Sc, vT, out, S, (int)MS, D, S,
        (long long)S * S, (long long)S, (long long)S * D, 4, 2, partial);
}

// Round 15
// 177.853 us; speedup vs baseline: 1.0467x; 1.0467x over previous
//
#include <hip/hip_runtime.h>
#include <hip/hip_bf16.h>

typedef unsigned short u16;
typedef __bf16 bf16x8 __attribute__((ext_vector_type(8)));
typedef float f32x4 __attribute__((ext_vector_type(4)));

__device__ __forceinline__ u16 f2bf(float f) {
    unsigned int u = __builtin_bit_cast(unsigned int, f);
    unsigned int r = u + 0x7FFFu + ((u >> 16) & 1u);
    return (u16)(r >> 16);
}

__device__ __forceinline__ void gload_lds16(const u16* g, u16* l) {
    __builtin_amdgcn_global_load_lds(
        (const __attribute__((address_space(1))) void*)(g),
        (__attribute__((address_space(3))) void*)(l), 16, 0, 0);
}

// ---- all fp32->bf16 converts in ONE launch ----
__global__ __launch_bounds__(256) void cvt_all(
    const float* __restrict__ x, const float* __restrict__ Wq,
    const float* __restrict__ Wk, const float* __restrict__ Wv,
    u16* __restrict__ xb, u16* __restrict__ wqkv)
{
    long long b = blockIdx.x;
    const float* src;
    u16* dst;
    long long i8;
    if (b < 4096) {
        src = x; dst = xb; i8 = b * 256 + threadIdx.x;
    } else {
        int wsel = (int)((b - 4096) >> 9);              // 0,1,2
        src = (wsel == 0) ? Wq : ((wsel == 1) ? Wk : Wv);
        dst = wqkv + (long long)wsel * 1024 * 1024;
        i8 = ((b - 4096) & 511) * 256 + threadIdx.x;
    }
    const float4* p = (const float4*)src + 2 * i8;
    float4 a = p[0], c = p[1];
    uint4 o;
    o.x = (unsigned)f2bf(a.x) | ((unsigned)f2bf(a.y) << 16);
    o.y = (unsigned)f2bf(a.z) | ((unsigned)f2bf(a.w) << 16);
    o.z = (unsigned)f2bf(c.x) | ((unsigned)f2bf(c.y) << 16);
    o.w = (unsigned)f2bf(c.z) | ((unsigned)f2bf(c.w) << 16);
    ((uint4*)dst)[i8] = o;
}

// ------- 4-phase bf16 GEMM body (r7/r11/r13 proven), C = A[M,K]*B[N,K]^T -------
// BM=256, BK=64, 512 thr = 8 waves. BN=256: 2x4 waves; BN=128: 4x2 waves.
// Subtiled LDS (conflict-free ds_read_b128, linear gload_lds); region-staggered
// staging; counted vmcnt once/tile; XCD-bijective chunk swizzle from flat id.
// EPI: 0 plain bf16; 1 exp2(acc*k) bf16 + row partials aux[row*8+bx];
//      2 f32 scaled by 1/sum(aux[row*8+0..7]) (inv hoisted BEFORE K-loop).
template <int BN, bool OUT_F32, int EPI>
__device__ __forceinline__ void gemm_body(
    u16* lds,
    const u16* __restrict__ A, const u16* __restrict__ B, void* __restrict__ Cv,
    int lda, int ldb, int ldc, int K,
    long long sAz, long long sBz, long long sCz,
    int z, int flat, int gx, int cw, int ch,
    float* __restrict__ aux)
{
    constexpr int WC = (BN == 256) ? 4 : 2;
    constexpr int ROWS = (BN == 256) ? 128 : 64;
    constexpr int MI = ROWS / 16;
    constexpr int MIh = MI / 2;
    constexpr int BLOADS = BN / 64;
    constexpr int BNK = BN * 64;

    u16* ldsB = lds + 32768;

    const int xcd = flat & 7, jj = flat >> 3;
    const int nCx = gx / cw;
    const int bx = (xcd % nCx) * cw + jj % cw;
    const int by = (xcd / nCx) * ch + jj / cw;

    A += (long long)z * sAz;
    B += (long long)z * sBz;

    const int tid  = threadIdx.x;
    const int lane = tid & 63;
    const int wave = tid >> 6;
    const int wr = wave / WC, wc = wave % WC;
    const int m0 = by << 8, n0 = bx * BN;
    const int NT = K >> 6;

    // epilogue coordinates (needed early for EPI==2 hoist)
    const int fl = lane & 15, fg = lane >> 4;
    const int er0 = m0 + wr * ROWS + fg * 4;
    const int ec0 = n0 + wc * 64 + fl;

    // EPI==2: hoist inverse row-sums before the K-loop (loads overlap GEMM;
    // oldest vmem ops -> in-loop counted vmcnt waits remain conservative)
    float iv[MI][4];
    if constexpr (EPI == 2) {
#pragma unroll
        for (int mi = 0; mi < MI; ++mi)
#pragma unroll
            for (int j = 0; j < 4; ++j) {
                const float* pr = aux + ((long long)z * 2048 + er0 + mi * 16 + j) * 8;
                float s = 0.f;
#pragma unroll
                for (int k = 0; k < 8; ++k) s += pr[k];
                iv[mi][j] = 1.0f / s;
            }
    }

    const u16* gAp[4];
    const u16* gBp[BLOADS];
#pragma unroll
    for (int i = 0; i < 4; ++i) {
        int s = tid + i * 512, row = ((s >> 7) << 4) | (s & 15), g = (s >> 4) & 7;
        gAp[i] = A + (long long)(m0 + row) * lda + g * 8;
    }
#pragma unroll
    for (int i = 0; i < BLOADS; ++i) {
        int s = tid + i * 512, row = ((s >> 7) << 4) | (s & 15), g = (s >> 4) & 7;
        gBp[i] = B + (long long)(n0 + row) * ldb + g * 8;
    }
    auto stA = [&](int kt, int buf, int i) {
        gload_lds16(gAp[i] + (long long)kt * 64, lds + buf * 16384 + (tid + i * 512) * 8);
    };
    auto stB = [&](int kt, int buf, int i) {
        gload_lds16(gBp[i] + (long long)kt * 64, ldsB + buf * BNK + (tid + i * 512) * 8);
    };

    f32x4 acc[MI][4] = {};

#pragma unroll
    for (int i = 0; i < 4; ++i) stA(0, 0, i);
#pragma unroll
    for (int i = 0; i < BLOADS; ++i) stB(0, 0, i);
#pragma unroll
    for (int i = 0; i < 4; ++i) stA(1, 1, i);
#pragma unroll
    for (int i = 0; i < BLOADS; ++i) stB(1, 1, i);
    if constexpr (BN == 256) asm volatile("s_waitcnt vmcnt(8)" ::: "memory");
    else                     asm volatile("s_waitcnt vmcnt(6)" ::: "memory");
    __builtin_amdgcn_s_barrier();

#pragma unroll 2
    for (int kt = 0; kt < NT; ++kt) {
        const int cur = kt & 1;
        const u16* sAc = lds  + cur * 16384 + lane * 8;
        const u16* sBc = ldsB + cur * BNK   + lane * 8;
        const bool st = (kt + 2 < NT);

        bf16x8 a[MIh][2], b0[2][2], b1[2][2];

        // ===== p0: read A-lo + B-lo; MFMA Q00 =====
#pragma unroll
        for (int mi = 0; mi < MIh; ++mi)
#pragma unroll
            for (int kk = 0; kk < 2; ++kk)
                a[mi][kk] = *(const bf16x8*)(sAc + ((wr * MI + mi) * 8 + kk * 4) * 128);
#pragma unroll
        for (int ni = 0; ni < 2; ++ni)
#pragma unroll
            for (int kk = 0; kk < 2; ++kk)
                b0[ni][kk] = *(const bf16x8*)(sBc + ((wc * 4 + ni) * 8 + kk * 4) * 128);
        __builtin_amdgcn_s_barrier();
        asm volatile("s_waitcnt lgkmcnt(0)" ::: "memory");
        __builtin_amdgcn_s_setprio(1);
#pragma unroll
        for (int kk = 0; kk < 2; ++kk)
#pragma unroll
            for (int mi = 0; mi < MIh; ++mi)
#pragma unroll
                for (int ni = 0; ni < 2; ++ni)
                    acc[mi][ni] = __builtin_amdgcn_mfma_f32_16x16x32_bf16(
                        a[mi][kk], b0[ni][kk], acc[mi][ni], 0, 0, 0);
        __builtin_amdgcn_s_setprio(0);
        __builtin_amdgcn_s_barrier();

        // ===== p1: stage A-lo regions; read B-hi; MFMA Q01 =====
        if constexpr (BN == 256) {
            if (st) { stA(kt + 2, cur, 0); stA(kt + 2, cur, 2); }
        }
#pragma unroll
        for (int ni = 0; ni < 2; ++ni)
#pragma unroll
            for (int kk = 0; kk < 2; ++kk)
                b1[ni][kk] = *(const bf16x8*)(sBc + ((wc * 4 + 2 + ni) * 8 + kk * 4) * 128);
        __builtin_amdgcn_s_barrier();
        asm volatile("s_waitcnt lgkmcnt(0)" ::: "memory");
        __builtin_amdgcn_s_setprio(1);
#pragma unroll
        for (int kk = 0; kk < 2; ++kk)
#pragma unroll
            for (int mi = 0; mi < MIh; ++mi)
#pragma unroll
                for (int ni = 0; ni < 2; ++ni)
                    acc[mi][2 + ni] = __builtin_amdgcn_mfma_f32_16x16x32_bf16(
                        a[mi][kk], b1[ni][kk], acc[mi][2 + ni], 0, 0, 0);
        __builtin_amdgcn_s_setprio(0);
        __builtin_amdgcn_s_barrier();

        // ===== p2: stage B-lo; read A-hi; MFMA Q10 =====
        if (st) {
            if constexpr (BN == 256) { stB(kt + 2, cur, 0); stB(kt + 2, cur, 1); }
            else                     { stB(kt + 2, cur, 0); }
        }
#pragma unroll
        for (int mi = 0; mi < MIh; ++mi)
#pragma unroll
            for (int kk = 0; kk < 2; ++kk)
                a[mi][kk] = *(const bf16x8*)(sAc + ((wr * MI + MIh + mi) * 8 + kk * 4) * 128);
        __builtin_amdgcn_s_barrier();
        asm volatile("s_waitcnt lgkmcnt(0)" ::: "memory");
        __builtin_amdgcn_s_setprio(1);
#pragma unroll
        for (int kk = 0; kk < 2; ++kk)
#pragma unroll
            for (int mi = 0; mi < MIh; ++mi)
#pragma unroll
                for (int ni = 0; ni < 2; ++ni)
                    acc[MIh + mi][ni] = __builtin_amdgcn_mfma_f32_16x16x32_bf16(
                        a[mi][kk], b0[ni][kk], acc[MIh + mi][ni], 0, 0, 0);
        __builtin_amdgcn_s_setprio(0);
        __builtin_amdgcn_s_barrier();

        // ===== p3: stage A-hi + B-hi; MFMA Q11; counted vmcnt =====
        if (st) {
            if constexpr (BN == 256) {
                stA(kt + 2, cur, 1); stA(kt + 2, cur, 3);
                stB(kt + 2, cur, 2); stB(kt + 2, cur, 3);
            } else {
                stA(kt + 2, cur, 0); stA(kt + 2, cur, 1);
                stA(kt + 2, cur, 2); stA(kt + 2, cur, 3);
                stB(kt + 2, cur, 1);
            }
        }
        __builtin_amdgcn_s_barrier();
        __builtin_amdgcn_s_setprio(1);
#pragma unroll
        for (int kk = 0; kk < 2; ++kk)
#pragma unroll
            for (int mi = 0; mi < MIh; ++mi)
#pragma unroll
                for (int ni = 0; ni < 2; ++ni)
                    acc[MIh + mi][2 + ni] = __builtin_amdgcn_mfma_f32_16x16x32_bf16(
                        a[mi][kk], b1[ni][kk], acc[MIh + mi][2 + ni], 0, 0, 0);
        __builtin_amdgcn_s_setprio(0);
        if (st) {
            if constexpr (BN == 256) asm volatile("s_waitcnt vmcnt(8)" ::: "memory");
            else                     asm volatile("s_waitcnt vmcnt(6)" ::: "memory");
        } else if (kt + 1 < NT) {
            asm volatile("s_waitcnt vmcnt(0)" ::: "memory");
        }
        __builtin_amdgcn_s_barrier();
    }

    // ---- epilogue: C/D layout col = lane&15, row = (lane>>4)*4+j ----
    if constexpr (EPI == 1) {
        // P~ = 2^(acc * log2e/32) -> bf16 C; row partials -> aux[(z*2048+row)*8+bx]
        u16* C = (u16*)Cv + (long long)z * sCz;
        float lsum[MI][4];
#pragma unroll
        for (int mi = 0; mi < MI; ++mi)
#pragma unroll
            for (int j = 0; j < 4; ++j) {
                float s = 0.f;
#pragma unroll
                for (int ni = 0; ni < 4; ++ni) {
                    float e = __builtin_amdgcn_exp2f(acc[mi][ni][j] * 0.04508422f);
                    C[(long long)(er0 + mi * 16 + j) * ldc + ec0 + ni * 16] = f2bf(e);
                    s += e;
                }
                lsum[mi][j] = s;
            }
#pragma unroll
        for (int mi = 0; mi < MI; ++mi)
#pragma unroll
            for (int j = 0; j < 4; ++j)
#pragma unroll
                for (int off = 1; off < 16; off <<= 1)
                    lsum[mi][j] += __shfl_xor(lsum[mi][j], off, 64);
        float (*rsbuf)[4] = reinterpret_cast<float(*)[4]>(lds);
        if (fl == 0) {
#pragma unroll
            for (int mi = 0; mi < MI; ++mi)
#pragma unroll
                for (int j = 0; j < 4; ++j)
                    rsbuf[wr * ROWS + mi * 16 + fg * 4 + j][wc] = lsum[mi][j];
        }
        __syncthreads();
        if (tid < 256) {
            float s = rsbuf[tid][0] + rsbuf[tid][1] + rsbuf[tid][2] + rsbuf[tid][3];
            aux[((long long)z * 2048 + m0 + tid) * 8 + bx] = s;
        }
    } else if constexpr (EPI == 2) {
        float* C = (float*)Cv + (long long)z * sCz;
#pragma unroll
        for (int mi = 0; mi < MI; ++mi)
#pragma unroll
            for (int ni = 0; ni < 4; ++ni)
#pragma unroll
                for (int j = 0; j < 4; ++j)
                    C[(long long)(er0 + mi * 16 + j) * ldc + ec0 + ni * 16] =
                        acc[mi][ni][j] * iv[mi][j];
    } else if constexpr (OUT_F32) {
        float* C = (float*)Cv + (long long)z * sCz;
#pragma unroll
        for (int mi = 0; mi < MI; ++mi)
#pragma unroll
            for (int ni = 0; ni < 4; ++ni)
#pragma unroll
                for (int j = 0; j < 4; ++j)
                    C[(long long)(er0 + mi * 16 + j) * ldc + ec0 + ni * 16] = acc[mi][ni][j];
    } else {
        u16* C = (u16*)Cv + (long long)z * sCz;
#pragma unroll
        for (int mi = 0; mi < MI; ++mi)
#pragma unroll
            for (int ni = 0; ni < 4; ++ni)
#pragma unroll
                for (int j = 0; j < 4; ++j)
                    C[(long long)(er0 + mi * 16 + j) * ldc + ec0 + ni * 16] = f2bf(acc[mi][ni][j]);
    }
}

// ---- fused QKV + vT (r13 exact shape): blocks 0-255 qk (BN=256),
// blocks 256-511 vT (BN=128, grid 64x4, chunk 8x4) -> both dispatch waves full.
__global__ __launch_bounds__(512, 2) void gemm_fused_qkv_vt(
    const u16* __restrict__ xb, const u16* __restrict__ wqk,
    const u16* __restrict__ wvb, u16* __restrict__ qk, u16* __restrict__ vT,
    int D, int MS)
{
    extern __shared__ u16 lds[];
    const int bid = blockIdx.x;
    if (bid < 256) {
        // qk[8192][2048] = xb * wqk^T : gx=8, gy=32, chunk 8x4
        gemm_body<256, false, 0>(lds, xb, wqk, qk, D, D, 2 * D, D,
                                 0, 0, 0, 0, bid, 8, 8, 4, nullptr);
    } else {
        // vT[1024][8192] = wvb * xb^T : gx=64, gy=4, chunk 8x4
        gemm_body<128, false, 0>(lds, wvb, xb, vT, D, D, MS, D,
                                 0, 0, 0, 0, bid - 256, 64, 8, 4, nullptr);
    }
}

// ---- standalone wrappers for scores / PV (batched via blockIdx.z) ----
template <int BN, bool OUT_F32, int EPI>
__global__ __launch_bounds__(512, 2) void gemm4p(
    const u16* __restrict__ A, const u16* __restrict__ B, void* __restrict__ Cv,
    int lda, int ldb, int ldc, int K,
    long long sAz, long long sBz, long long sCz, int cw, int ch,
    float* __restrict__ aux)
{
    extern __shared__ u16 lds[];
    const int flat = blockIdx.x + gridDim.x * blockIdx.y;
    gemm_body<BN, OUT_F32, EPI>(lds, A, B, Cv, lda, ldb, ldc, K,
                                sAz, sBz, sCz, blockIdx.z, flat,
                                gridDim.x, cw, ch, aux);
}

extern "C" void kernel_launch(void* const* d_in, const int* in_sizes, int n_in,
                              void* d_out, int out_size, void* d_ws, size_t ws_size,
                              hipStream_t stream) {
    const float* x  = (const float*)d_in[0];   // [4,2048,1024]
    const float* Wq = (const float*)d_in[1];   // [1024,1024]
    const float* Wk = (const float*)d_in[2];
    const float* Wv = (const float*)d_in[3];
    float* out = (float*)d_out;                // [4,2048,1024] fp32

    const int B = 4, S = 2048, D = 1024;
    const long long MS = (long long)B * S;     // 8192

    u16* Sc  = (u16*)d_ws;                     // 4*2048*2048
    u16* xb  = Sc;                             // 8192*1024 (overlays Sc; dead after fused GEMM)
    u16* wqk = Sc  + (long long)B * S * S;     // Wq,Wk then Wv (contiguous)
    u16* wvb = wqk + 2 * D * D;
    u16* qk  = wvb + D * D;                    // 8192*2048
    u16* vT  = qk  + MS * 2 * D;               // 1024*8192
    float* partial = (float*)(vT + MS * D);    // 8192*8 f32
    size_t need = (size_t)2 * ((long long)B * S * S + 3 * D * D + MS * 2 * D + MS * D)
                + (size_t)4 * (MS * 8);
    if (ws_size < need) return;

    (void)hipFuncSetAttribute(reinterpret_cast<const void*>(&gemm_fused_qkv_vt),
                        hipFuncAttributeMaxDynamicSharedMemorySize, 131072);
    (void)hipFuncSetAttribute(reinterpret_cast<const void*>(&gemm4p<256, false, 1>),
                        hipFuncAttributeMaxDynamicSharedMemorySize, 131072);
    (void)hipFuncSetAttribute(reinterpret_cast<const void*>(&gemm4p<128, true, 2>),
                        hipFuncAttributeMaxDynamicSharedMemorySize, 98304);

    // 1) all converts in one launch
    cvt_all<<<4096 + 3 * 512, 256, 0, stream>>>(x, Wq, Wk, Wv, xb, wqk);

    // 2) fused: qk = xb*[Wq;Wk]^T (blocks 0-255) + vT = Wv*xb^T (blocks 256-511)
    gemm_fused_qkv_vt<<<512, 512, 131072, stream>>>(
        xb, wqk, wvb, qk, vT, D, (int)MS);

    // 3) P~ = exp(q k^T / 32) bf16 + row partials   grid (8,8,4); chunk 2x4
    gemm4p<256, false, 1><<<dim3(S / 256, S / 256, B), 512, 131072, stream>>>(
        qk, qk + D, Sc, 2 * D, 2 * D, S, D,
        (long long)S * 2 * D, (long long)S * 2 * D, (long long)S * S, 2, 4, partial);

    // 4) out = (P~ * vT^T) * (1/rowsum)   grid (8,8,4); chunk 4x2; fp32 out
    gemm4p<128, true, 2><<<dim3(D / 128, S / 256, B), 512, 98304, stream>>>(
        Sc, vT, out, S, (int)MS, D, S,
        (long long)S * S, (long long)S, (long long)S * D, 4, 2, partial);
}

// Round 16
// 176.021 us; speedup vs baseline: 1.0576x; 1.0104x over previous
//
#include <hip/hip_runtime.h>
#include <hip/hip_bf16.h>

typedef unsigned short u16;
typedef __bf16 bf16x8 __attribute__((ext_vector_type(8)));
typedef float f32x4 __attribute__((ext_vector_type(4)));

__device__ __forceinline__ u16 f2bf(float f) {
    unsigned int u = __builtin_bit_cast(unsigned int, f);
    unsigned int r = u + 0x7FFFu + ((u >> 16) & 1u);
    return (u16)(r >> 16);
}

__device__ __forceinline__ void gload_lds16(const u16* g, u16* l) {
    __builtin_amdgcn_global_load_lds(
        (const __attribute__((address_space(1))) void*)(g),
        (__attribute__((address_space(3))) void*)(l), 16, 0, 0);
}

// ---- all fp32->bf16 converts in ONE launch ----
__global__ __launch_bounds__(256) void cvt_all(
    const float* __restrict__ x, const float* __restrict__ Wq,
    const float* __restrict__ Wk, const float* __restrict__ Wv,
    u16* __restrict__ xb, u16* __restrict__ wqkv)
{
    long long b = blockIdx.x;
    const float* src;
    u16* dst;
    long long i8;
    if (b < 4096) {
        src = x; dst = xb; i8 = b * 256 + threadIdx.x;
    } else {
        int wsel = (int)((b - 4096) >> 9);              // 0,1,2
        src = (wsel == 0) ? Wq : ((wsel == 1) ? Wk : Wv);
        dst = wqkv + (long long)wsel * 1024 * 1024;
        i8 = ((b - 4096) & 511) * 256 + threadIdx.x;
    }
    const float4* p = (const float4*)src + 2 * i8;
    float4 a = p[0], c = p[1];
    uint4 o;
    o.x = (unsigned)f2bf(a.x) | ((unsigned)f2bf(a.y) << 16);
    o.y = (unsigned)f2bf(a.z) | ((unsigned)f2bf(a.w) << 16);
    o.z = (unsigned)f2bf(c.x) | ((unsigned)f2bf(c.y) << 16);
    o.w = (unsigned)f2bf(c.z) | ((unsigned)f2bf(c.w) << 16);
    ((uint4*)dst)[i8] = o;
}

// ------- 4-phase bf16 GEMM body (r7/r11/r13 proven), C = A[M,K]*B[N,K]^T -------
// BM=256, BK=64, 512 thr = 8 waves. BN=256: 2x4 waves; BN=128: 4x2 waves.
// Subtiled LDS (conflict-free ds_read_b128, linear gload_lds); region-staggered
// staging; counted vmcnt once/tile; XCD-bijective chunk swizzle from flat id.
// EPI: 0 plain bf16; 1 exp2(acc*k) bf16 + row partials aux[row*8+bx];
//      2 f32 scaled by 1/sum(aux[row*8+0..7]).
template <int BN, bool OUT_F32, int EPI>
__device__ __forceinline__ void gemm_body(
    u16* lds,
    const u16* __restrict__ A, const u16* __restrict__ B, void* __restrict__ Cv,
    int lda, int ldb, int ldc, int K,
    long long sAz, long long sBz, long long sCz,
    int z, int flat, int gx, int cw, int ch,
    float* __restrict__ aux)
{
    constexpr int WC = (BN == 256) ? 4 : 2;
    constexpr int ROWS = (BN == 256) ? 128 : 64;
    constexpr int MI = ROWS / 16;
    constexpr int MIh = MI / 2;
    constexpr int BLOADS = BN / 64;
    constexpr int BNK = BN * 64;

    u16* ldsB = lds + 32768;

    const int xcd = flat & 7, jj = flat >> 3;
    const int nCx = gx / cw;
    const int bx = (xcd % nCx) * cw + jj % cw;
    const int by = (xcd / nCx) * ch + jj / cw;

    A += (long long)z * sAz;
    B += (long long)z * sBz;

    const int tid  = threadIdx.x;
    const int lane = tid & 63;
    const int wave = tid >> 6;
    const int wr = wave / WC, wc = wave % WC;
    const int m0 = by << 8, n0 = bx * BN;
    const int NT = K >> 6;

    const u16* gAp[4];
    const u16* gBp[BLOADS];
#pragma unroll
    for (int i = 0; i < 4; ++i) {
        int s = tid + i * 512, row = ((s >> 7) << 4) | (s & 15), g = (s >> 4) & 7;
        gAp[i] = A + (long long)(m0 + row) * lda + g * 8;
    }
#pragma unroll
    for (int i = 0; i < BLOADS; ++i) {
        int s = tid + i * 512, row = ((s >> 7) << 4) | (s & 15), g = (s >> 4) & 7;
        gBp[i] = B + (long long)(n0 + row) * ldb + g * 8;
    }
    auto stA = [&](int kt, int buf, int i) {
        gload_lds16(gAp[i] + (long long)kt * 64, lds + buf * 16384 + (tid + i * 512) * 8);
    };
    auto stB = [&](int kt, int buf, int i) {
        gload_lds16(gBp[i] + (long long)kt * 64, ldsB + buf * BNK + (tid + i * 512) * 8);
    };

    f32x4 acc[MI][4] = {};

#pragma unroll
    for (int i = 0; i < 4; ++i) stA(0, 0, i);
#pragma unroll
    for (int i = 0; i < BLOADS; ++i) stB(0, 0, i);
#pragma unroll
    for (int i = 0; i < 4; ++i) stA(1, 1, i);
#pragma unroll
    for (int i = 0; i < BLOADS; ++i) stB(1, 1, i);
    if constexpr (BN == 256) asm volatile("s_waitcnt vmcnt(8)" ::: "memory");
    else                     asm volatile("s_waitcnt vmcnt(6)" ::: "memory");
    __builtin_amdgcn_s_barrier();

#pragma unroll 2
    for (int kt = 0; kt < NT; ++kt) {
        const int cur = kt & 1;
        const u16* sAc = lds  + cur * 16384 + lane * 8;
        const u16* sBc = ldsB + cur * BNK   + lane * 8;
        const bool st = (kt + 2 < NT);

        bf16x8 a[MIh][2], b0[2][2], b1[2][2];

        // ===== p0: read A-lo + B-lo; MFMA Q00 =====
#pragma unroll
        for (int mi = 0; mi < MIh; ++mi)
#pragma unroll
            for (int kk = 0; kk < 2; ++kk)
                a[mi][kk] = *(const bf16x8*)(sAc + ((wr * MI + mi) * 8 + kk * 4) * 128);
#pragma unroll
        for (int ni = 0; ni < 2; ++ni)
#pragma unroll
            for (int kk = 0; kk < 2; ++kk)
                b0[ni][kk] = *(const bf16x8*)(sBc + ((wc * 4 + ni) * 8 + kk * 4) * 128);
        __builtin_amdgcn_s_barrier();
        asm volatile("s_waitcnt lgkmcnt(0)" ::: "memory");
        __builtin_amdgcn_s_setprio(1);
#pragma unroll
        for (int kk = 0; kk < 2; ++kk)
#pragma unroll
            for (int mi = 0; mi < MIh; ++mi)
#pragma unroll
                for (int ni = 0; ni < 2; ++ni)
                    acc[mi][ni] = __builtin_amdgcn_mfma_f32_16x16x32_bf16(
                        a[mi][kk], b0[ni][kk], acc[mi][ni], 0, 0, 0);
        __builtin_amdgcn_s_setprio(0);
        __builtin_amdgcn_s_barrier();

        // ===== p1: stage A-lo regions; read B-hi; MFMA Q01 =====
        if constexpr (BN == 256) {
            if (st) { stA(kt + 2, cur, 0); stA(kt + 2, cur, 2); }
        }
#pragma unroll
        for (int ni = 0; ni < 2; ++ni)
#pragma unroll
            for (int kk = 0; kk < 2; ++kk)
                b1[ni][kk] = *(const bf16x8*)(sBc + ((wc * 4 + 2 + ni) * 8 + kk * 4) * 128);
        __builtin_amdgcn_s_barrier();
        asm volatile("s_waitcnt lgkmcnt(0)" ::: "memory");
        __builtin_amdgcn_s_setprio(1);
#pragma unroll
        for (int kk = 0; kk < 2; ++kk)
#pragma unroll
            for (int mi = 0; mi < MIh; ++mi)
#pragma unroll
                for (int ni = 0; ni < 2; ++ni)
                    acc[mi][2 + ni] = __builtin_amdgcn_mfma_f32_16x16x32_bf16(
                        a[mi][kk], b1[ni][kk], acc[mi][2 + ni], 0, 0, 0);
        __builtin_amdgcn_s_setprio(0);
        __builtin_amdgcn_s_barrier();

        // ===== p2: stage B-lo; read A-hi; MFMA Q10 =====
        if (st) {
            if constexpr (BN == 256) { stB(kt + 2, cur, 0); stB(kt + 2, cur, 1); }
            else                     { stB(kt + 2, cur, 0); }
        }
#pragma unroll
        for (int mi = 0; mi < MIh; ++mi)
#pragma unroll
            for (int kk = 0; kk < 2; ++kk)
                a[mi][kk] = *(const bf16x8*)(sAc + ((wr * MI + MIh + mi) * 8 + kk * 4) * 128);
        __builtin_amdgcn_s_barrier();
        asm volatile("s_waitcnt lgkmcnt(0)" ::: "memory");
        __builtin_amdgcn_s_setprio(1);
#pragma unroll
        for (int kk = 0; kk < 2; ++kk)
#pragma unroll
            for (int mi = 0; mi < MIh; ++mi)
#pragma unroll
                for (int ni = 0; ni < 2; ++ni)
                    acc[MIh + mi][ni] = __builtin_amdgcn_mfma_f32_16x16x32_bf16(
                        a[mi][kk], b0[ni][kk], acc[MIh + mi][ni], 0, 0, 0);
        __builtin_amdgcn_s_setprio(0);
        __builtin_amdgcn_s_barrier();

        // ===== p3: stage A-hi + B-hi; MFMA Q11; counted vmcnt =====
        if (st) {
            if constexpr (BN == 256) {
                stA(kt + 2, cur, 1); stA(kt + 2, cur, 3);
                stB(kt + 2, cur, 2); stB(kt + 2, cur, 3);
            } else {
                stA(kt + 2, cur, 0); stA(kt + 2, cur, 1);
                stA(kt + 2, cur, 2); stA(kt + 2, cur, 3);
                stB(kt + 2, cur, 1);
            }
        }
        __builtin_amdgcn_s_barrier();
        __builtin_amdgcn_s_setprio(1);
#pragma unroll
        for (int kk = 0; kk < 2; ++kk)
#pragma unroll
            for (int mi = 0; mi < MIh; ++mi)
#pragma unroll
                for (int ni = 0; ni < 2; ++ni)
                    acc[MIh + mi][2 + ni] = __builtin_amdgcn_mfma_f32_16x16x32_bf16(
                        a[mi][kk], b1[ni][kk], acc[MIh + mi][2 + ni], 0, 0, 0);
        __builtin_amdgcn_s_setprio(0);
        if (st) {
            if constexpr (BN == 256) asm volatile("s_waitcnt vmcnt(8)" ::: "memory");
            else                     asm volatile("s_waitcnt vmcnt(6)" ::: "memory");
        } else if (kt + 1 < NT) {
            asm volatile("s_waitcnt vmcnt(0)" ::: "memory");
        }
        __builtin_amdgcn_s_barrier();
    }

    // ---- epilogue: C/D layout col = lane&15, row = (lane>>4)*4+j ----
    const int fl = lane & 15, fg = lane >> 4;
    const int er0 = m0 + wr * ROWS + fg * 4;
    const int ec0 = n0 + wc * 64 + fl;

    if constexpr (EPI == 1) {
        // P~ = 2^(acc * log2e/32) -> bf16 C; row partials -> aux[(z*2048+row)*8+bx]
        u16* C = (u16*)Cv + (long long)z * sCz;
        float lsum[MI][4];
#pragma unroll
        for (int mi = 0; mi < MI; ++mi)
#pragma unroll
            for (int j = 0; j < 4; ++j) {
                float s = 0.f;
#pragma unroll
                for (int ni = 0; ni < 4; ++ni) {
                    float e = __builtin_amdgcn_exp2f(acc[mi][ni][j] * 0.04508422f);
                    C[(long long)(er0 + mi * 16 + j) * ldc + ec0 + ni * 16] = f2bf(e);
                    s += e;
                }
                lsum[mi][j] = s;
            }
#pragma unroll
        for (int mi = 0; mi < MI; ++mi)
#pragma unroll
            for (int j = 0; j < 4; ++j)
#pragma unroll
                for (int off = 1; off < 16; off <<= 1)
                    lsum[mi][j] += __shfl_xor(lsum[mi][j], off, 64);
        float (*rsbuf)[4] = reinterpret_cast<float(*)[4]>(lds);
        if (fl == 0) {
#pragma unroll
            for (int mi = 0; mi < MI; ++mi)
#pragma unroll
                for (int j = 0; j < 4; ++j)
                    rsbuf[wr * ROWS + mi * 16 + fg * 4 + j][wc] = lsum[mi][j];
        }
        __syncthreads();
        if (tid < 256) {
            float s = rsbuf[tid][0] + rsbuf[tid][1] + rsbuf[tid][2] + rsbuf[tid][3];
            aux[((long long)z * 2048 + m0 + tid) * 8 + bx] = s;
        }
    } else if constexpr (EPI == 2) {
        // f32 C scaled by 1/rowsum (partials summed in-epilogue)
        float* C = (float*)Cv + (long long)z * sCz;
        float iv[MI][4];
#pragma unroll
        for (int mi = 0; mi < MI; ++mi)
#pragma unroll
            for (int j = 0; j < 4; ++j) {
                const float* pr = aux + ((long long)z * 2048 + er0 + mi * 16 + j) * 8;
                float s = 0.f;
#pragma unroll
                for (int k = 0; k < 8; ++k) s += pr[k];
                iv[mi][j] = 1.0f / s;
            }
#pragma unroll
        for (int mi = 0; mi < MI; ++mi)
#pragma unroll
            for (int ni = 0; ni < 4; ++ni)
#pragma unroll
                for (int j = 0; j < 4; ++j)
                    C[(long long)(er0 + mi * 16 + j) * ldc + ec0 + ni * 16] =
                        acc[mi][ni][j] * iv[mi][j];
    } else if constexpr (OUT_F32) {
        float* C = (float*)Cv + (long long)z * sCz;
#pragma unroll
        for (int mi = 0; mi < MI; ++mi)
#pragma unroll
            for (int ni = 0; ni < 4; ++ni)
#pragma unroll
                for (int j = 0; j < 4; ++j)
                    C[(long long)(er0 + mi * 16 + j) * ldc + ec0 + ni * 16] = acc[mi][ni][j];
    } else {
        u16* C = (u16*)Cv + (long long)z * sCz;
#pragma unroll
        for (int mi = 0; mi < MI; ++mi)
#pragma unroll
            for (int ni = 0; ni < 4; ++ni)
#pragma unroll
                for (int j = 0; j < 4; ++j)
                    C[(long long)(er0 + mi * 16 + j) * ldc + ec0 + ni * 16] = f2bf(acc[mi][ni][j]);
    }
}

// ---- fused QKV + vT (r13 exact): blocks 0-255 qk (BN=256),
// blocks 256-511 vT (BN=128, grid 64x4, chunk 8x4) -> both dispatch waves full.
__global__ __launch_bounds__(512, 2) void gemm_fused_qkv_vt(
    const u16* __restrict__ xb, const u16* __restrict__ wqk,
    const u16* __restrict__ wvb, u16* __restrict__ qk, u16* __restrict__ vT,
    int D, int MS)
{
    extern __shared__ u16 lds[];
    const int bid = blockIdx.x;
    if (bid < 256) {
        // qk[8192][2048] = xb * wqk^T : gx=8, gy=32, chunk 8x4
        gemm_body<256, false, 0>(lds, xb, wqk, qk, D, D, 2 * D, D,
                                 0, 0, 0, 0, bid, 8, 8, 4, nullptr);
    } else {
        // vT[1024][8192] = wvb * xb^T : gx=64, gy=4, chunk 8x4
        gemm_body<128, false, 0>(lds, wvb, xb, vT, D, D, MS, D,
                                 0, 0, 0, 0, bid - 256, 64, 8, 4, nullptr);
    }
}

// ---- standalone wrappers for scores / PV (batched via blockIdx.z) ----
template <int BN, bool OUT_F32, int EPI>
__global__ __launch_bounds__(512, 2) void gemm4p(
    const u16* __restrict__ A, const u16* __restrict__ B, void* __restrict__ Cv,
    int lda, int ldb, int ldc, int K,
    long long sAz, long long sBz, long long sCz, int cw, int ch,
    float* __restrict__ aux)
{
    extern __shared__ u16 lds[];
    const int flat = blockIdx.x + gridDim.x * blockIdx.y;
    gemm_body<BN, OUT_F32, EPI>(lds, A, B, Cv, lda, ldb, ldc, K,
                                sAz, sBz, sCz, blockIdx.z, flat,
                                gridDim.x, cw, ch, aux);
}

extern "C" void kernel_launch(void* const* d_in, const int* in_sizes, int n_in,
                              void* d_out, int out_size, void* d_ws, size_t ws_size,
                              hipStream_t stream) {
    const float* x  = (const float*)d_in[0];   // [4,2048,1024]
    const float* Wq = (const float*)d_in[1];   // [1024,1024]
    const float* Wk = (const float*)d_in[2];
    const float* Wv = (const float*)d_in[3];
    float* out = (float*)d_out;                // [4,2048,1024] fp32

    const int B = 4, S = 2048, D = 1024;
    const long long MS = (long long)B * S;     // 8192

    u16* Sc  = (u16*)d_ws;                     // 4*2048*2048
    u16* xb  = Sc;                             // 8192*1024 (overlays Sc; dead after fused GEMM)
    u16* wqk = Sc  + (long long)B * S * S;     // Wq,Wk then Wv (contiguous)
    u16* wvb = wqk + 2 * D * D;
    u16* qk  = wvb + D * D;                    // 8192*2048
    u16* vT  = qk  + MS * 2 * D;               // 1024*8192
    float* partial = (float*)(vT + MS * D);    // 8192*8 f32
    size_t need = (size_t)2 * ((long long)B * S * S + 3 * D * D + MS * 2 * D + MS * D)
                + (size_t)4 * (MS * 8);
    if (ws_size < need) return;

    (void)hipFuncSetAttribute(reinterpret_cast<const void*>(&gemm_fused_qkv_vt),
                        hipFuncAttributeMaxDynamicSharedMemorySize, 131072);
    (void)hipFuncSetAttribute(reinterpret_cast<const void*>(&gemm4p<256, false, 1>),
                        hipFuncAttributeMaxDynamicSharedMemorySize, 131072);
    (void)hipFuncSetAttribute(reinterpret_cast<const void*>(&gemm4p<128, true, 2>),
                        hipFuncAttributeMaxDynamicSharedMemorySize, 98304);

    // 1) all converts in one launch
    cvt_all<<<4096 + 3 * 512, 256, 0, stream>>>(x, Wq, Wk, Wv, xb, wqk);

    // 2) fused: qk = xb*[Wq;Wk]^T (blocks 0-255) + vT = Wv*xb^T (blocks 256-511)
    gemm_fused_qkv_vt<<<512, 512, 131072, stream>>>(
        xb, wqk, wvb, qk, vT, D, (int)MS);

    // 3) P~ = exp(q k^T / 32) bf16 + row partials   grid (8,8,4); chunk 2x4
    gemm4p<256, false, 1><<<dim3(S / 256, S / 256, B), 512, 131072, stream>>>(
        qk, qk + D, Sc, 2 * D, 2 * D, S, D,
        (long long)S * 2 * D, (long long)S * 2 * D, (long long)S * S, 2, 4, partial);

    // 4) out = (P~ * vT^T) * (1/rowsum)   grid (8,8,4); chunk 4x2; fp32 out
    gemm4p<128, true, 2><<<dim3(D / 128, S / 256, B), 512, 98304, stream>>>(
        Sc, vT, out, S, (int)MS, D, S,
        (long long)S * S, (long long)S, (long long)S * D, 4, 2, partial);
}